// Round 4
// baseline (221.104 us; speedup 1.0000x reference)
//
#include <hip/hip_runtime.h>
#include <math.h>

#define NB 16
#define NA 5
#define NH 96
#define NW 96
#define MAXT 50
#define NC 40
#define CH 45      // 5 + NUM_CLASSES
#define TGT_W 53   // 13 + NUM_CLASSES
#define NCELL (NH*NW)          // 9216
#define NTGT (NB*MAXT)         // 800
#define TOTF4 8294400          // NB*NA*NH*NW*CH / 4
#define S8 1036800             // TOTF4/8 ; % 45 == 0  (phase invariant)
#define CONF_BLOCKS 1013       // ceil(S8/1024)
#define CORR_BLOCKS 250        // 250*16 waves = 4000 = NB*MAXT*NA slots
#define NSLOT 4000
#define IGNORE_THRES 0.5f

// anchors / SCALE
__device__ __constant__ float c_AW[5] = {1.f, 2.f, 4.f, 2.f, 4.f};
__device__ __constant__ float c_AH[5] = {1.f, 2.f, 4.f, 4.f, 2.f};

// ws layout (bytes):
//  @0      acc[10] doubles: [1]=cmf_bce corr [2]=cmf cnt corr [3]=mask_bce
//          [4]=cls ce [5..8]=x,y,w,h sq err [9]=nM   ([0] unused)
//  @80     corG[16] ints (per-batch nCorrect)
//  @160    wlist[4000][8] ints:
//          [0]=ca(20b)|ma<<20|cma<<21|valid<<22  [1]=lbl
//          [2]=fx [3]=fy [4]=tw [5]=th (float bits) [6,7] pad
//  @512160 partial_d[1013] doubles
//  @520264 partial_i[1013] ints

__device__ __forceinline__ float softplusf(float p) {
    return fmaxf(p, 0.f) + log1pf(expf(-fabsf(p)));
}

__device__ __forceinline__ float pick(float4 q, int comp) {
    return comp == 0 ? q.x : comp == 1 ? q.y : comp == 2 ? q.z : q.w;
}

// ---------- Kernel 1: per-batch target analysis + ownership, emit worklist ----------
__global__ __launch_bounds__(1024) void tgt_build(
    const float* __restrict__ pred, const float* __restrict__ tgt,
    const int* __restrict__ tsz, double* acc, int* corG, int* wlist) {
    __shared__ int   s_key[MAXT], s_best[MAXT], s_ign[MAXT], s_lbl[MAXT];
    __shared__ float s_fx[MAXT], s_fy[MAXT], s_gw[MAXT], s_gh[MAXT];
    __shared__ int   s_cor[MAXT];

    const int b = blockIdx.x;
    const int wave = threadIdx.x >> 6, lane = threadIdx.x & 63;

    if (b == 0 && threadIdx.x < 10) acc[threadIdx.x] = 0.0;  // kernel-2 accumulators

    const int size_b = tsz[b];

    // ---- Phase 1: wave w handles targets t = w, w+16, ... ----
    for (int t = wave; t < MAXT; t += 16) {
        const bool valid = t < size_b;
        const float* row = tgt + ((size_t)b * MAXT + t) * TGT_W;
        const float inv_s = 0.0625f;
        float gx = row[0] * inv_s, gy = row[1] * inv_s;
        float gh_ = row[3] * inv_s, gw_ = row[4] * inv_s;
        int gi = (int)gx, gj = (int)gy;

        // label argmax across lanes (first-max)
        float lv = (lane < NC) ? row[13 + lane] : -1e30f;
        int   li = (lane < NC) ? lane : (1 << 30);
        #pragma unroll
        for (int off = 32; off; off >>= 1) {
            float ov = __shfl_xor(lv, off);
            int   oi = __shfl_xor(li, off);
            if (ov > lv || (ov == lv && oi < li)) { lv = ov; li = oi; }
        }
        int lbl = li;

        // anchor IoUs (redundant per lane)
        float best_iou = -1e30f; int best = 0; int ign = 0;
        #pragma unroll
        for (int a = 0; a < 5; ++a) {
            float iw = fmaxf(fminf(gw_, c_AW[a]) + 1.f, 0.f);
            float ih = fmaxf(fminf(gh_, c_AH[a]) + 1.f, 0.f);
            float inter = iw * ih;
            float iou = inter / ((gw_ + 1.f) * (gh_ + 1.f) +
                                 (c_AW[a] + 1.f) * (c_AH[a] + 1.f) - inter + 1e-16f);
            if (iou > IGNORE_THRES) ign |= (1 << a);
            if (iou > best_iou) { best_iou = iou; best = a; }
        }

        // coalesced pred fragment at (b,best,gj,gi)
        size_t pbase = ((((size_t)b * NA + best) * NH + gj) * NW + gi) * CH;
        float pv = (lane < CH) ? pred[pbase + lane] : -1e30f;
        float pc = __shfl(pv, 0);
        float px = __shfl(pv, 1) + (float)gi;
        float py = __shfl(pv, 2) + (float)gj;
        float ph = expf(__shfl(pv, 3)) * c_AH[best];
        float pw = expf(__shfl(pv, 4)) * c_AW[best];

        float gx1 = gx - gw_ * 0.5f, gx2 = gx + gw_ * 0.5f;
        float gy1 = gy - gh_ * 0.5f, gy2 = gy + gh_ * 0.5f;
        float px1 = px - pw * 0.5f, px2 = px + pw * 0.5f;
        float py1 = py - ph * 0.5f, py2 = py + ph * 0.5f;
        float iw2 = fmaxf(fminf(gx2, px2) - fmaxf(gx1, px1) + 1.f, 0.f);
        float ih2 = fmaxf(fminf(gy2, py2) - fmaxf(gy1, py1) + 1.f, 0.f);
        float inter2 = iw2 * ih2;
        float ga = (gx2 - gx1 + 1.f) * (gy2 - gy1 + 1.f);
        float pa = (px2 - px1 + 1.f) * (py2 - py1 + 1.f);
        float iou2 = inter2 / (ga + pa - inter2 + 1e-16f);

        // pred cls argmax across lanes (first-max)
        float cv = (lane >= 5 && lane < CH) ? pv : -1e30f;
        int   ci = (lane >= 5 && lane < CH) ? (lane - 5) : (1 << 30);
        #pragma unroll
        for (int off = 32; off; off >>= 1) {
            float ov = __shfl_xor(cv, off);
            int   oi = __shfl_xor(ci, off);
            if (ov > cv || (ov == cv && oi < ci)) { cv = ov; ci = oi; }
        }
        bool correct = valid && (iou2 > 0.5f) && (ci == lbl) && (pc > 0.5f);

        if (lane == 0) {
            s_key[t] = valid ? (gj * NW + gi) : -1;
            s_best[t] = best; s_ign[t] = ign; s_lbl[t] = lbl;
            s_fx[t] = gx - (float)gi; s_fy[t] = gy - (float)gj;
            s_gw[t] = gw_; s_gh[t] = gh_;
            s_cor[t] = correct ? 1 : 0;
        }
    }
    __syncthreads();

    if (threadIdx.x == 0) {
        int c = 0;
        for (int t = 0; t < MAXT; ++t) c += s_cor[t];
        corG[b] = c;
    }

    // ---- Phase 2: one thread per target; owner = last valid with same key ----
    const int t = threadIdx.x;
    if (t >= MAXT) return;
    int* slot0 = wlist + ((size_t)(b * MAXT + t) * NA) * 8;

    const int myKey = s_key[t];
    bool owner = (myKey >= 0);
    if (owner)
        for (int u = t + 1; u < MAXT; ++u)
            if (s_key[u] == myKey) { owner = false; break; }

    if (!owner) {
        #pragma unroll
        for (int a = 0; a < 5; ++a) slot0[a * 8] = 0;   // invalid
        return;
    }

    int cm = 0x1F, m = 0;
    int w[5] = {-1, -1, -1, -1, -1};
    for (int u = 0; u < MAXT; ++u) {
        if (s_key[u] != myKey) continue;
        cm &= ~s_ign[u];
        int bn = s_best[u];
        cm |= (1 << bn); m |= (1 << bn);
        w[bn] = u;
    }
    #pragma unroll
    for (int a = 0; a < 5; ++a) {
        int* e = slot0 + a * 8;
        int ca = (b * NA + a) * NCELL + myKey;    // < 2^20
        int ma = (m >> a) & 1, cma = (cm >> a) & 1;
        e[0] = ca | (ma << 20) | (cma << 21) | (1 << 22);
        if (ma) {
            int u = w[a];
            e[1] = s_lbl[u];
            e[2] = __float_as_int(s_fx[u]);
            e[3] = __float_as_int(s_fy[u]);
            e[4] = __float_as_int(logf(s_gw[u] / c_AW[a] + 1e-16f));
            e[5] = __float_as_int(logf(s_gh[u] / c_AH[a] + 1e-16f));
        }
    }
}

// ---------- Kernel 2: corrections (blocks 0..249) + conf stream (250..1262) ----------
__global__ __launch_bounds__(1024) void mega(
    const float* __restrict__ pred, double* acc, const int* __restrict__ wlist,
    double* partial_d, int* partial_i) {
    const int wave = threadIdx.x >> 6, lane = threadIdx.x & 63;

    if (blockIdx.x < CORR_BLOCKS) {
        // ----- corrections: one wave per worklist slot -----
        const int s = blockIdx.x * 16 + wave;       // < 4000
        const int* e = wlist + (size_t)s * 8;
        double loc[9];
        #pragma unroll
        for (int c = 0; c < 9; ++c) loc[c] = 0.0;

        int flags = e[0];
        if (flags & (1 << 22)) {
            int ca = flags & 0xFFFFF;
            int ma = (flags >> 20) & 1, cma = (flags >> 21) & 1;
            size_t base = (size_t)ca * CH;
            float v = (lane < CH) ? pred[base + lane] : -1e30f;
            float p = __shfl(v, 0);
            float s0 = softplusf(p);
            int cmf = (cma != ma) ? 1 : 0;
            loc[0] = (cmf ? (double)(s0 - p * (float)ma) : 0.0) - (double)s0;
            loc[1] = (double)(cmf - 1);
            if (ma) {
                loc[2] = (double)(s0 - p);
                loc[8] = 1.0;
                float x = __shfl(v, 1), y = __shfl(v, 2);
                float hh = __shfl(v, 3), wv = __shfl(v, 4);
                float fx = __int_as_float(e[2]), fy = __int_as_float(e[3]);
                float tw_ = __int_as_float(e[4]), th_ = __int_as_float(e[5]);
                int lbl = e[1];
                loc[4] = (double)((x - fx) * (x - fx));
                loc[5] = (double)((y - fy) * (y - fy));
                loc[6] = (double)((wv - tw_) * (wv - tw_));
                loc[7] = (double)((hh - th_) * (hh - th_));
                float cvv = (lane >= 5 && lane < CH) ? v : -1e30f;
                float mx = cvv;
                #pragma unroll
                for (int off = 32; off; off >>= 1) mx = fmaxf(mx, __shfl_xor(mx, off));
                float ex = (lane >= 5 && lane < CH) ? expf(v - mx) : 0.f;
                #pragma unroll
                for (int off = 32; off; off >>= 1) ex += __shfl_xor(ex, off);
                float cll = __shfl(v, 5 + lbl);
                loc[3] = (double)(logf(ex) + mx - cll);
            }
        }

        __shared__ double red[16][9];
        if (lane == 0) {
            #pragma unroll
            for (int c = 0; c < 9; ++c) red[wave][c] = loc[c];
        }
        __syncthreads();
        if (threadIdx.x < 9) {
            double sum = 0.0;
            #pragma unroll
            for (int wv = 0; wv < 16; ++wv) sum += red[wv][threadIdx.x];
            if (sum != 0.0) atomicAdd(&acc[1 + threadIdx.x], sum);
        }
    } else {
        // ----- conf stream: 8 independent float4 loads per thread -----
        const int cb = blockIdx.x - CORR_BLOCKS;
        const int tid = cb * 1024 + threadIdx.x;
        const float4* pf = (const float4*)pred;
        float bce = 0.f; int prop = 0;
        if (tid < S8) {
            float4 q0 = pf[tid];
            float4 q1 = pf[tid + S8];
            float4 q2 = pf[tid + 2 * S8];
            float4 q3 = pf[tid + 3 * S8];
            float4 q4 = pf[tid + 4 * S8];
            float4 q5 = pf[tid + 5 * S8];
            float4 q6 = pf[tid + 6 * S8];
            float4 q7 = pf[tid + 7 * S8];
            int r = tid % 45;            // same phase for all 8 (S8 % 45 == 0)
            if (r == 0 || r == 11 || r == 22 || r == 33) {
                int comp = r / 11;
                float c0 = pick(q0, comp), c1 = pick(q1, comp);
                float c2 = pick(q2, comp), c3 = pick(q3, comp);
                float c4 = pick(q4, comp), c5 = pick(q5, comp);
                float c6 = pick(q6, comp), c7 = pick(q7, comp);
                bce = softplusf(c0) + softplusf(c1) + softplusf(c2) + softplusf(c3)
                    + softplusf(c4) + softplusf(c5) + softplusf(c6) + softplusf(c7);
                prop = (c0 > 0.f) + (c1 > 0.f) + (c2 > 0.f) + (c3 > 0.f)
                     + (c4 > 0.f) + (c5 > 0.f) + (c6 > 0.f) + (c7 > 0.f);
            }
        }
        #pragma unroll
        for (int off = 32; off; off >>= 1) {
            bce  += __shfl_down(bce, off);
            prop += __shfl_down(prop, off);
        }
        __shared__ float sb[16];
        __shared__ int   sp[16];
        if (lane == 0) { sb[wave] = bce; sp[wave] = prop; }
        __syncthreads();
        if (threadIdx.x == 0) {
            float tb = 0.f; int tp = 0;
            #pragma unroll
            for (int wv = 0; wv < 16; ++wv) { tb += sb[wv]; tp += sp[wv]; }
            partial_d[cb] = (double)tb;
            partial_i[cb] = tp;
        }
    }
}

// ---------- Kernel 3: finalize ----------
__global__ __launch_bounds__(256) void finalize(
    const double* __restrict__ acc, const int* __restrict__ corG,
    const int* __restrict__ tsz,
    const double* __restrict__ partial_d, const int* __restrict__ partial_i,
    float* out) {
    __shared__ double sd[256];
    __shared__ int    si[256];
    double db = 0.0; int ip = 0;
    for (int i = threadIdx.x; i < CONF_BLOCKS; i += 256) { db += partial_d[i]; ip += partial_i[i]; }
    sd[threadIdx.x] = db; si[threadIdx.x] = ip;
    __syncthreads();
    for (int off = 128; off; off >>= 1) {
        if (threadIdx.x < off) {
            sd[threadIdx.x] += sd[threadIdx.x + off];
            si[threadIdx.x] += si[threadIdx.x + off];
        }
        __syncthreads();
    }
    if (threadIdx.x != 0) return;
    double sum_bce0 = sd[0];
    int nProp = si[0];
    int nCor = 0, nGT = 0;
    for (int b = 0; b < NB; ++b) { nCor += corG[b]; nGT += tsz[b]; }

    double nM = acc[9];
    double inv_nM = 1.0 / (nM > 0.0 ? nM : 1e-16);
    double l_coord = (acc[5] + acc[6] + acc[7] + acc[8]) * inv_nM;
    double sum_cmf = (double)(NB * NA * NH * NW) + acc[2];
    double l_conf = (sum_bce0 + acc[1]) / sum_cmf + acc[3] * inv_nM;
    double l_cls = (1.0 / (double)NB) * acc[4] * inv_nM;
    double loss = l_coord + l_conf + l_cls;
    float recall = (float)nCor / (float)(nGT > 1 ? nGT : 1);
    float precision = (nProp > 0) ? ((float)nCor / fmaxf((float)nProp, 1.f)) : 1.f;
    out[0] = (float)loss;
    out[1] = (float)l_coord;
    out[2] = (float)l_conf;
    out[3] = (float)l_cls;
    out[4] = recall;
    out[5] = precision;
}

extern "C" void kernel_launch(void* const* d_in, const int* in_sizes, int n_in,
                              void* d_out, int out_size, void* d_ws, size_t ws_size,
                              hipStream_t stream) {
    const float* pred = (const float*)d_in[0];
    const float* tgt  = (const float*)d_in[1];
    const int*   tsz  = (const int*)d_in[2];
    float* out = (float*)d_out;

    double* acc = (double*)d_ws;
    int* corG   = (int*)((char*)d_ws + 80);
    int* wlist  = (int*)((char*)d_ws + 160);
    double* partial_d = (double*)((char*)d_ws + 512160);
    int*    partial_i = (int*)((char*)d_ws + 520264);

    tgt_build<<<NB, 1024, 0, stream>>>(pred, tgt, tsz, acc, corG, wlist);
    mega<<<CORR_BLOCKS + CONF_BLOCKS, 1024, 0, stream>>>(pred, acc, wlist,
                                                         partial_d, partial_i);
    finalize<<<1, 256, 0, stream>>>(acc, corG, tsz, partial_d, partial_i, out);
}

// Round 5
// 215.162 us; speedup vs baseline: 1.0276x; 1.0276x over previous
//
#include <hip/hip_runtime.h>
#include <math.h>

#define NB 16
#define NA 5
#define NH 96
#define NW 96
#define MAXT 50
#define NC 40
#define CH 45      // 5 + NUM_CLASSES
#define TGT_W 53   // 13 + NUM_CLASSES
#define NCELL (NH*NW)          // 9216
#define NTOT (NB*NA*NH*NW)     // 737280 cells
#define CONF_BLOCKS 720        // 720*1024 = 737280, one thread per cell
#define CORR_BLOCKS 250        // 250*16 waves = 4000 = NB*MAXT*NA slots
#define IGNORE_THRES 0.5f

// anchors / SCALE
__device__ __constant__ float c_AW[5] = {1.f, 2.f, 4.f, 2.f, 4.f};
__device__ __constant__ float c_AH[5] = {1.f, 2.f, 4.f, 4.f, 2.f};

// ws layout (bytes):
//  @0      acc[10] doubles: [1]=cmf_bce corr [2]=cmf cnt corr [3]=mask_bce
//          [4]=cls ce [5..8]=x,y,w,h sq err [9]=nM   ([0] unused)
//  @80     corG[16] ints (per-batch nCorrect)
//  @160    wlist[4000][8] ints:
//          [0]=ca(20b)|ma<<20|cma<<21|valid<<22  [1]=lbl
//          [2]=fx [3]=fy [4]=tw [5]=th (float bits) [6,7] pad
//  @512160 partial_d[720] doubles
//  @517920 partial_i[720] ints

__device__ __forceinline__ float softplusf(float p) {
    return fmaxf(p, 0.f) + log1pf(expf(-fabsf(p)));
}

// ---------- Kernel 1: per-batch target analysis + ownership, emit worklist ----------
__global__ __launch_bounds__(1024) void tgt_build(
    const float* __restrict__ pred, const float* __restrict__ tgt,
    const int* __restrict__ tsz, double* acc, int* corG, int* wlist) {
    __shared__ int   s_key[MAXT], s_best[MAXT], s_ign[MAXT], s_lbl[MAXT];
    __shared__ float s_fx[MAXT], s_fy[MAXT], s_gw[MAXT], s_gh[MAXT];
    __shared__ int   s_cor[MAXT];

    const int b = blockIdx.x;
    const int wave = threadIdx.x >> 6, lane = threadIdx.x & 63;

    if (b == 0 && threadIdx.x < 10) acc[threadIdx.x] = 0.0;  // kernel-2 accumulators

    const int size_b = tsz[b];

    // ---- Phase 1: wave w handles targets t = w, w+16, ... ----
    for (int t = wave; t < MAXT; t += 16) {
        const bool valid = t < size_b;
        const float* row = tgt + ((size_t)b * MAXT + t) * TGT_W;
        const float inv_s = 0.0625f;
        float gx = row[0] * inv_s, gy = row[1] * inv_s;
        float gh_ = row[3] * inv_s, gw_ = row[4] * inv_s;
        int gi = (int)gx, gj = (int)gy;

        // label argmax across lanes (first-max)
        float lv = (lane < NC) ? row[13 + lane] : -1e30f;
        int   li = (lane < NC) ? lane : (1 << 30);
        #pragma unroll
        for (int off = 32; off; off >>= 1) {
            float ov = __shfl_xor(lv, off);
            int   oi = __shfl_xor(li, off);
            if (ov > lv || (ov == lv && oi < li)) { lv = ov; li = oi; }
        }
        int lbl = li;

        // anchor IoUs (redundant per lane)
        float best_iou = -1e30f; int best = 0; int ign = 0;
        #pragma unroll
        for (int a = 0; a < 5; ++a) {
            float iw = fmaxf(fminf(gw_, c_AW[a]) + 1.f, 0.f);
            float ih = fmaxf(fminf(gh_, c_AH[a]) + 1.f, 0.f);
            float inter = iw * ih;
            float iou = inter / ((gw_ + 1.f) * (gh_ + 1.f) +
                                 (c_AW[a] + 1.f) * (c_AH[a] + 1.f) - inter + 1e-16f);
            if (iou > IGNORE_THRES) ign |= (1 << a);
            if (iou > best_iou) { best_iou = iou; best = a; }
        }

        // coalesced pred fragment at (b,best,gj,gi)
        size_t pbase = ((((size_t)b * NA + best) * NH + gj) * NW + gi) * CH;
        float pv = (lane < CH) ? pred[pbase + lane] : -1e30f;
        float pc = __shfl(pv, 0);
        float px = __shfl(pv, 1) + (float)gi;
        float py = __shfl(pv, 2) + (float)gj;
        float ph = expf(__shfl(pv, 3)) * c_AH[best];
        float pw = expf(__shfl(pv, 4)) * c_AW[best];

        float gx1 = gx - gw_ * 0.5f, gx2 = gx + gw_ * 0.5f;
        float gy1 = gy - gh_ * 0.5f, gy2 = gy + gh_ * 0.5f;
        float px1 = px - pw * 0.5f, px2 = px + pw * 0.5f;
        float py1 = py - ph * 0.5f, py2 = py + ph * 0.5f;
        float iw2 = fmaxf(fminf(gx2, px2) - fmaxf(gx1, px1) + 1.f, 0.f);
        float ih2 = fmaxf(fminf(gy2, py2) - fmaxf(gy1, py1) + 1.f, 0.f);
        float inter2 = iw2 * ih2;
        float ga = (gx2 - gx1 + 1.f) * (gy2 - gy1 + 1.f);
        float pa = (px2 - px1 + 1.f) * (py2 - py1 + 1.f);
        float iou2 = inter2 / (ga + pa - inter2 + 1e-16f);

        // pred cls argmax across lanes (first-max)
        float cv = (lane >= 5 && lane < CH) ? pv : -1e30f;
        int   ci = (lane >= 5 && lane < CH) ? (lane - 5) : (1 << 30);
        #pragma unroll
        for (int off = 32; off; off >>= 1) {
            float ov = __shfl_xor(cv, off);
            int   oi = __shfl_xor(ci, off);
            if (ov > cv || (ov == cv && oi < ci)) { cv = ov; ci = oi; }
        }
        bool correct = valid && (iou2 > 0.5f) && (ci == lbl) && (pc > 0.5f);

        if (lane == 0) {
            s_key[t] = valid ? (gj * NW + gi) : -1;
            s_best[t] = best; s_ign[t] = ign; s_lbl[t] = lbl;
            s_fx[t] = gx - (float)gi; s_fy[t] = gy - (float)gj;
            s_gw[t] = gw_; s_gh[t] = gh_;
            s_cor[t] = correct ? 1 : 0;
        }
    }
    __syncthreads();

    if (threadIdx.x == 0) {
        int c = 0;
        for (int t = 0; t < MAXT; ++t) c += s_cor[t];
        corG[b] = c;
    }

    // ---- Phase 2: one thread per target; owner = last valid with same key ----
    const int t = threadIdx.x;
    if (t >= MAXT) return;
    int* slot0 = wlist + ((size_t)(b * MAXT + t) * NA) * 8;

    const int myKey = s_key[t];
    bool owner = (myKey >= 0);
    if (owner)
        for (int u = t + 1; u < MAXT; ++u)
            if (s_key[u] == myKey) { owner = false; break; }

    if (!owner) {
        #pragma unroll
        for (int a = 0; a < 5; ++a) slot0[a * 8] = 0;   // invalid
        return;
    }

    int cm = 0x1F, m = 0;
    int w[5] = {-1, -1, -1, -1, -1};
    for (int u = 0; u < MAXT; ++u) {
        if (s_key[u] != myKey) continue;
        cm &= ~s_ign[u];
        int bn = s_best[u];
        cm |= (1 << bn); m |= (1 << bn);
        w[bn] = u;
    }
    #pragma unroll
    for (int a = 0; a < 5; ++a) {
        int* e = slot0 + a * 8;
        int ca = (b * NA + a) * NCELL + myKey;    // < 2^20
        int ma = (m >> a) & 1, cma = (cm >> a) & 1;
        e[0] = ca | (ma << 20) | (cma << 21) | (1 << 22);
        if (ma) {
            int u = w[a];
            e[1] = s_lbl[u];
            e[2] = __float_as_int(s_fx[u]);
            e[3] = __float_as_int(s_fy[u]);
            e[4] = __float_as_int(logf(s_gw[u] / c_AW[a] + 1e-16f));
            e[5] = __float_as_int(logf(s_gh[u] / c_AH[a] + 1e-16f));
        }
    }
}

// ---------- Kernel 2: corrections (blocks 0..249) + sparse conf (250..969) ----------
__global__ __launch_bounds__(1024) void mega(
    const float* __restrict__ pred, double* acc, const int* __restrict__ wlist,
    double* partial_d, int* partial_i) {
    const int wave = threadIdx.x >> 6, lane = threadIdx.x & 63;

    if (blockIdx.x < CORR_BLOCKS) {
        // ----- corrections: one wave per worklist slot -----
        const int s = blockIdx.x * 16 + wave;       // < 4000
        const int* e = wlist + (size_t)s * 8;
        double loc[9];
        #pragma unroll
        for (int c = 0; c < 9; ++c) loc[c] = 0.0;

        int flags = e[0];
        if (flags & (1 << 22)) {
            int ca = flags & 0xFFFFF;
            int ma = (flags >> 20) & 1, cma = (flags >> 21) & 1;
            size_t base = (size_t)ca * CH;
            float v = (lane < CH) ? pred[base + lane] : -1e30f;
            float p = __shfl(v, 0);
            float s0 = softplusf(p);
            int cmf = (cma != ma) ? 1 : 0;
            loc[0] = (cmf ? (double)(s0 - p * (float)ma) : 0.0) - (double)s0;
            loc[1] = (double)(cmf - 1);
            if (ma) {
                loc[2] = (double)(s0 - p);
                loc[8] = 1.0;
                float x = __shfl(v, 1), y = __shfl(v, 2);
                float hh = __shfl(v, 3), wv = __shfl(v, 4);
                float fx = __int_as_float(e[2]), fy = __int_as_float(e[3]);
                float tw_ = __int_as_float(e[4]), th_ = __int_as_float(e[5]);
                int lbl = e[1];
                loc[4] = (double)((x - fx) * (x - fx));
                loc[5] = (double)((y - fy) * (y - fy));
                loc[6] = (double)((wv - tw_) * (wv - tw_));
                loc[7] = (double)((hh - th_) * (hh - th_));
                float cvv = (lane >= 5 && lane < CH) ? v : -1e30f;
                float mx = cvv;
                #pragma unroll
                for (int off = 32; off; off >>= 1) mx = fmaxf(mx, __shfl_xor(mx, off));
                float ex = (lane >= 5 && lane < CH) ? expf(v - mx) : 0.f;
                #pragma unroll
                for (int off = 32; off; off >>= 1) ex += __shfl_xor(ex, off);
                float cll = __shfl(v, 5 + lbl);
                loc[3] = (double)(logf(ex) + mx - cll);
            }
        }

        __shared__ double red[16][9];
        if (lane == 0) {
            #pragma unroll
            for (int c = 0; c < 9; ++c) red[wave][c] = loc[c];
        }
        __syncthreads();
        if (threadIdx.x < 9) {
            double sum = 0.0;
            #pragma unroll
            for (int wv = 0; wv < 16; ++wv) sum += red[wv][threadIdx.x];
            if (sum != 0.0) atomicAdd(&acc[1 + threadIdx.x], sum);
        }
    } else {
        // ----- sparse conf: one thread per cell, single 4-B load at stride 180 B -----
        const int cb = blockIdx.x - CORR_BLOCKS;
        const int cell = cb * 1024 + threadIdx.x;   // exactly NTOT threads
        float p = pred[(size_t)cell * CH];
        float bce = softplusf(p);
        int prop = (p > 0.f) ? 1 : 0;

        #pragma unroll
        for (int off = 32; off; off >>= 1) {
            bce  += __shfl_down(bce, off);
            prop += __shfl_down(prop, off);
        }
        __shared__ float sb[16];
        __shared__ int   sp[16];
        if (lane == 0) { sb[wave] = bce; sp[wave] = prop; }
        __syncthreads();
        if (threadIdx.x == 0) {
            float tb = 0.f; int tp = 0;
            #pragma unroll
            for (int wv = 0; wv < 16; ++wv) { tb += sb[wv]; tp += sp[wv]; }
            partial_d[cb] = (double)tb;
            partial_i[cb] = tp;
        }
    }
}

// ---------- Kernel 3: finalize ----------
__global__ __launch_bounds__(256) void finalize(
    const double* __restrict__ acc, const int* __restrict__ corG,
    const int* __restrict__ tsz,
    const double* __restrict__ partial_d, const int* __restrict__ partial_i,
    float* out) {
    __shared__ double sd[256];
    __shared__ int    si[256];
    double db = 0.0; int ip = 0;
    for (int i = threadIdx.x; i < CONF_BLOCKS; i += 256) { db += partial_d[i]; ip += partial_i[i]; }
    sd[threadIdx.x] = db; si[threadIdx.x] = ip;
    __syncthreads();
    for (int off = 128; off; off >>= 1) {
        if (threadIdx.x < off) {
            sd[threadIdx.x] += sd[threadIdx.x + off];
            si[threadIdx.x] += si[threadIdx.x + off];
        }
        __syncthreads();
    }
    if (threadIdx.x != 0) return;
    double sum_bce0 = sd[0];
    int nProp = si[0];
    int nCor = 0, nGT = 0;
    for (int b = 0; b < NB; ++b) { nCor += corG[b]; nGT += tsz[b]; }

    double nM = acc[9];
    double inv_nM = 1.0 / (nM > 0.0 ? nM : 1e-16);
    double l_coord = (acc[5] + acc[6] + acc[7] + acc[8]) * inv_nM;
    double sum_cmf = (double)(NB * NA * NH * NW) + acc[2];
    double l_conf = (sum_bce0 + acc[1]) / sum_cmf + acc[3] * inv_nM;
    double l_cls = (1.0 / (double)NB) * acc[4] * inv_nM;
    double loss = l_coord + l_conf + l_cls;
    float recall = (float)nCor / (float)(nGT > 1 ? nGT : 1);
    float precision = (nProp > 0) ? ((float)nCor / fmaxf((float)nProp, 1.f)) : 1.f;
    out[0] = (float)loss;
    out[1] = (float)l_coord;
    out[2] = (float)l_conf;
    out[3] = (float)l_cls;
    out[4] = recall;
    out[5] = precision;
}

extern "C" void kernel_launch(void* const* d_in, const int* in_sizes, int n_in,
                              void* d_out, int out_size, void* d_ws, size_t ws_size,
                              hipStream_t stream) {
    const float* pred = (const float*)d_in[0];
    const float* tgt  = (const float*)d_in[1];
    const int*   tsz  = (const int*)d_in[2];
    float* out = (float*)d_out;

    double* acc = (double*)d_ws;
    int* corG   = (int*)((char*)d_ws + 80);
    int* wlist  = (int*)((char*)d_ws + 160);
    double* partial_d = (double*)((char*)d_ws + 512160);
    int*    partial_i = (int*)((char*)d_ws + 517920);

    tgt_build<<<NB, 1024, 0, stream>>>(pred, tgt, tsz, acc, corG, wlist);
    mega<<<CORR_BLOCKS + CONF_BLOCKS, 1024, 0, stream>>>(pred, acc, wlist,
                                                         partial_d, partial_i);
    finalize<<<1, 256, 0, stream>>>(acc, corG, tsz, partial_d, partial_i, out);
}